// Round 1
// baseline (4492.786 us; speedup 1.0000x reference)
//
#include <hip/hip_runtime.h>
#include <math.h>

// Problem constants (B=4, H=8, L=2048, DK=DV=32)
#define LQ   2048
#define DKD  32
#define TQ   32          // q rows per block
#define KT   128         // k per tile
#define NT   (LQ / KT)   // 16 tiles

// LDS layouts (all 32-float rows, XOR-swizzled, no padding):
//   Qs[32][32]  : elem (q,db)  at q*32  + ((db ^ (q&7))<<2)        (db = d/4)
//   KP[128][32] : K elem (r,db) at r*32 + ((db ^ ((r>>2)&7))<<2)
//                 then reused per-wave: P(row,kg) f4 at g*1024 + row*32 + ((kg^ (row&7))<<2)
//                 then reused for ctx merge, same layout as P.
//   Vt[128][32] : same swizzle as K.
// Column ownership: thread (qg,kg) owns columns g*32 + 4*kg .. +3  -> float4 I/O on
// res/mask/scores (128B per 8-lane group, coalesced).

__device__ __forceinline__ void gload_lds16(const float* g, float* l) {
    __builtin_amdgcn_global_load_lds(
        (__attribute__((address_space(1))) void*)g,
        (__attribute__((address_space(3))) void*)l,
        16, 0, 0);
}

__global__ __launch_bounds__(256, 4)
void sdpa_fused(const float* __restrict__ Q,
                const float* __restrict__ K,
                const float* __restrict__ V,
                const int*   __restrict__ mask,
                const float* __restrict__ res,
                float* __restrict__ outCtx,
                float* __restrict__ outSc)
{
    __shared__ __align__(16) float Qs[TQ * 32];    //  4096 B
    __shared__ __align__(16) float KP[KT * 32];    // 16384 B (K tile / P / ctx union)
    __shared__ __align__(16) float Vt[KT * 32];    // 16384 B
    __shared__ float mred[4 * TQ];                 //   512 B
    __shared__ float lred[4 * TQ];                 //   512 B  -> total 37888 B, 4 blocks/CU

    const int t    = threadIdx.x;
    const int g    = t >> 6;          // wave 0..3 (owns k-quarter g)
    const int lane = t & 63;
    const int qg   = lane >> 3;       // 0..7
    const int kg   = lane & 7;        // 0..7

    // XCD-aware bijective swizzle (2048 blocks, 8 XCDs -> contiguous 256-block chunks)
    const int bx = (blockIdx.x & 7) * 256 + (blockIdx.x >> 3);
    const int bh = bx >> 6;           // 0..31
    const int qt = bx & 63;           // 0..63

    const int rowQ0 = bh * LQ + qt * TQ;   // all index math fits in int32

    // ---- stage Q tile (32x32), swizzled ----
    {
        int q  = t >> 3;
        int db = t & 7;
        float4 qv = *(const float4*)(Q + (rowQ0 + q) * DKD + (db << 2));
        *(float4*)(Qs + q * 32 + (((db ^ q) & 7) << 2)) = qv;
    }

    float m[4], l[4], acc[4][4];
    #pragma unroll
    for (int i = 0; i < 4; i++) {
        m[i] = -1e30f; l[i] = 0.f;
        acc[i][0] = acc[i][1] = acc[i][2] = acc[i][3] = 0.f;
    }

    const float scale = 0.17677669529663687f;  // 1/sqrt(32)
    const int wb = (t >> 6) << 6;              // wave-uniform: first thread idx of wave

    for (int kt = 0; kt < NT; kt++) {
        __syncthreads();  // prev-tile PV / Qs staging complete before restaging KP,Vt

        // ---- stage K,V tile: async global->LDS, swizzle applied on SOURCE address ----
        const int k0g = bh * LQ + kt * KT;
        #pragma unroll
        for (int u = 0; u < 4; u++) {
            int f   = t + 256 * u;            // 0..1023 float4 slots
            int kr  = f >> 3;                 // k row 0..127
            int dbs = (f ^ (kr >> 2)) & 7;    // db ^ ((kr>>2)&7)  (pre-swizzled column)
            const float* gk = K + (k0g + kr) * DKD + (dbs << 2);
            const float* gv = V + (k0g + kr) * DKD + (dbs << 2);
            float* lbase = (float*)0;         // per-chunk wave-uniform LDS base (floats)
            int fb = (wb + 256 * u) << 2;
            lbase = KP + fb;  gload_lds16(gk, lbase);
            lbase = Vt + fb;  gload_lds16(gv, lbase);
        }

        // ---- early res/mask vector loads (consumed after QK^T) ----
        const int colBase = kt * KT + g * 32 + (kg << 2);
        float4 rv4[4]; int4 mv4[4];
        #pragma unroll
        for (int i = 0; i < 4; i++) {
            const int rb = (rowQ0 + qg + 8*i) * LQ + colBase;
            rv4[i] = *(const float4*)(res + rb);
            mv4[i] = *(const int4*)(mask + rb);
        }

        __syncthreads();  // drains vmcnt(0): K/V in LDS, rv4/mv4 in regs

        // pack mask into 16 bits, freeing 15 VGPRs for the compute phase
        int mbits = 0;
        #pragma unroll
        for (int i = 0; i < 4; i++) {
            mbits |= (mv4[i].x != 0) << (4*i);
            mbits |= (mv4[i].y != 0) << (4*i + 1);
            mbits |= (mv4[i].z != 0) << (4*i + 2);
            mbits |= (mv4[i].w != 0) << (4*i + 3);
        }

        // ---- QK^T: 4q x 4k micro-tile, k = g*32 + 4*kg + j ----
        float S[4][4];
        #pragma unroll
        for (int i = 0; i < 4; i++) { S[i][0]=S[i][1]=S[i][2]=S[i][3]=0.f; }
        #pragma unroll
        for (int s = 0; s < 8; s++) {
            float4 qf[4], kf[4];
            #pragma unroll
            for (int i = 0; i < 4; i++)
                qf[i] = *(const float4*)(Qs + (qg + 8*i) * 32 + (((s ^ qg) & 7) << 2));
            #pragma unroll
            for (int j = 0; j < 4; j++) {
                int r = g * 32 + (kg << 2) + j;
                kf[j] = *(const float4*)(KP + r * 32 + (((s ^ kg) & 7) << 2));
            }
            #pragma unroll
            for (int i = 0; i < 4; i++) {
                #pragma unroll
                for (int j = 0; j < 4; j++) {
                    S[i][j] += qf[i].x * kf[j].x;
                    S[i][j] += qf[i].y * kf[j].y;
                    S[i][j] += qf[i].z * kf[j].z;
                    S[i][j] += qf[i].w * kf[j].w;
                }
            }
        }

        // ---- epilogue: scale + res, mask, emit scores (float4, coalesced) ----
        #pragma unroll
        for (int i = 0; i < 4; i++) {
            const int rb  = (rowQ0 + qg + 8*i) * LQ + colBase;
            const int msk = mbits >> (4*i);
            float4 sv;
            sv.x = (msk & 1)        ? -1e9f : (S[i][0] * scale + rv4[i].x);
            sv.y = ((msk >> 1) & 1) ? -1e9f : (S[i][1] * scale + rv4[i].y);
            sv.z = ((msk >> 2) & 1) ? -1e9f : (S[i][2] * scale + rv4[i].z);
            sv.w = ((msk >> 3) & 1) ? -1e9f : (S[i][3] * scale + rv4[i].w);
            *(float4*)(outSc + rb) = sv;
            S[i][0] = sv.x; S[i][1] = sv.y; S[i][2] = sv.z; S[i][3] = sv.w;
        }

        // ---- per-wave online softmax; P overwrites this wave's K quarter in KP ----
        #pragma unroll
        for (int i = 0; i < 4; i++) {
            float mloc = fmaxf(fmaxf(S[i][0], S[i][1]), fmaxf(S[i][2], S[i][3]));
            mloc = fmaxf(mloc, __shfl_xor(mloc, 1));
            mloc = fmaxf(mloc, __shfl_xor(mloc, 2));
            mloc = fmaxf(mloc, __shfl_xor(mloc, 4));
            float mn = fmaxf(m[i], mloc);
            float al = __expf(m[i] - mn);
            m[i] = mn;
            float4 p;
            p.x = __expf(S[i][0] - mn);
            p.y = __expf(S[i][1] - mn);
            p.z = __expf(S[i][2] - mn);
            p.w = __expf(S[i][3] - mn);
            int row = qg + 8*i;
            *(float4*)(KP + (g << 10) + row * 32 + (((kg ^ qg) & 7) << 2)) = p;
            float ps = p.x + p.y + p.z + p.w;
            ps += __shfl_xor(ps, 1);
            ps += __shfl_xor(ps, 2);
            ps += __shfl_xor(ps, 4);
            l[i] = l[i] * al + ps;
            acc[i][0] *= al; acc[i][1] *= al; acc[i][2] *= al; acc[i][3] *= al;
        }

        // ---- PV over own quarter (same-wave KP round trip, no barrier) ----
        #pragma unroll
        for (int s2 = 0; s2 < 8; s2++) {
            float4 pf[4];
            #pragma unroll
            for (int i = 0; i < 4; i++)
                pf[i] = *(const float4*)(KP + (g << 10) + (qg + 8*i) * 32
                                            + (((s2 ^ qg) & 7) << 2));
            #pragma unroll
            for (int j2 = 0; j2 < 4; j2++) {
                int r = g * 32 + (s2 << 2) + j2;
                float4 vf = *(const float4*)(Vt + r * 32 + (((kg ^ s2) & 7) << 2));
                #pragma unroll
                for (int i = 0; i < 4; i++) {
                    float p = (j2 == 0) ? pf[i].x : (j2 == 1) ? pf[i].y
                            : (j2 == 2) ? pf[i].z : pf[i].w;
                    acc[i][0] += p * vf.x;
                    acc[i][1] += p * vf.y;
                    acc[i][2] += p * vf.z;
                    acc[i][3] += p * vf.w;
                }
            }
        }
    }

    // ---- merge the 4 per-wave (m, l, acc) states; ctx reuses KP sections ----
    #pragma unroll
    for (int i = 0; i < 4; i++) {
        int row = qg + 8*i;
        float4 cv; cv.x = acc[i][0]; cv.y = acc[i][1]; cv.z = acc[i][2]; cv.w = acc[i][3];
        *(float4*)(KP + (g << 10) + row * 32 + (((kg ^ qg) & 7) << 2)) = cv;
        if (kg == 0) {
            mred[g * TQ + row] = m[i];
            lred[g * TQ + row] = l[i];
        }
    }
    __syncthreads();
    {
        int q  = t >> 3;
        int db = t & 7;
        float m0 = mred[q], m1 = mred[TQ + q], m2 = mred[2*TQ + q], m3 = mred[3*TQ + q];
        float mm = fmaxf(fmaxf(m0, m1), fmaxf(m2, m3));
        float w0 = __expf(m0 - mm), w1 = __expf(m1 - mm);
        float w2 = __expf(m2 - mm), w3 = __expf(m3 - mm);
        float lt = lred[q]*w0 + lred[TQ+q]*w1 + lred[2*TQ+q]*w2 + lred[3*TQ+q]*w3;
        float inv = 1.0f / lt;
        int co = q * 32 + (((db ^ q) & 7) << 2);
        float4 c0 = *(const float4*)(KP + co);
        float4 c1 = *(const float4*)(KP + 1024 + co);
        float4 c2 = *(const float4*)(KP + 2048 + co);
        float4 c3 = *(const float4*)(KP + 3072 + co);
        float4 o;
        o.x = (c0.x*w0 + c1.x*w1 + c2.x*w2 + c3.x*w3) * inv;
        o.y = (c0.y*w0 + c1.y*w1 + c2.y*w2 + c3.y*w3) * inv;
        o.z = (c0.z*w0 + c1.z*w1 + c2.z*w2 + c3.z*w3) * inv;
        o.w = (c0.w*w0 + c1.w*w1 + c2.w*w2 + c3.w*w3) * inv;
        *(float4*)(outCtx + (rowQ0 + q) * DKD + (db << 2)) = o;
    }
}

extern "C" void kernel_launch(void* const* d_in, const int* in_sizes, int n_in,
                              void* d_out, int out_size, void* d_ws, size_t ws_size,
                              hipStream_t stream) {
    // setup_inputs order: Q, K, V, attn_mask, res_att
    const float* Q    = (const float*)d_in[0];
    const float* K    = (const float*)d_in[1];
    const float* V    = (const float*)d_in[2];
    const int*   mask = (const int*)d_in[3];
    const float* res  = (const float*)d_in[4];
    float* outCtx = (float*)d_out;                                  // [4,8,2048,32]
    float* outSc  = (float*)d_out + (size_t)4 * 8 * 2048 * 32;      // [4,8,2048,2048]
    sdpa_fused<<<dim3(2048), dim3(256), 0, stream>>>(Q, K, V, mask, res, outCtx, outSc);
}